// Round 6
// baseline (562.695 us; speedup 1.0000x reference)
//
#include <hip/hip_runtime.h>
#include <math.h>

// Problem constants: T=1024, B=8, H=8, N=32. D = H*N*N = 8192.
// ============================================================================
// PROBE ROUND: byte-identical to the banked 463.8us kernel EXCEPT scan_kernel
// is launched TWICE (idempotent: same inputs -> same outputs). The dur_us
// delta vs 463.8 directly measures one scan_kernel dispatch, which the
// top-5-truncated rocprof table cannot show (< 158us fill rows).
// ============================================================================
#define T_STEPS 1024
#define NBH     64          // B*H
#define NTILE   65536       // T*B*H

static __device__ __forceinline__ float fast_rcp(float x) {
  return __builtin_amdgcn_rcpf(x);
}
static __device__ __forceinline__ float fast_sigmoid(float x) {
  return fast_rcp(1.0f + __expf(-x));
}
// tanh(x) where y = 2x is passed: tanh = 1 - 2/(1+e^{2x})
static __device__ __forceinline__ float fast_tanh2(float y) {
  return 1.0f - 2.0f * fast_rcp(1.0f + __expf(y));
}

// DPP add: x + lane-permuted(x). CTRL is a compile-time DPP control.
template <int CTRL>
static __device__ __forceinline__ float dpp_add(float x) {
  int y = __builtin_amdgcn_update_dpp(0, __float_as_int(x), CTRL, 0xF, 0xF, true);
  return x + __int_as_float(y);
}

// Butterfly sum over each 16-lane group; result in all 16 lanes. Pure DPP.
static __device__ __forceinline__ float red16(float x) {
  x = dpp_add<0xB1>(x);    // quad_perm(1,0,3,2)  == xor 1
  x = dpp_add<0x4E>(x);    // quad_perm(2,3,0,1)  == xor 2
  x = dpp_add<0x141>(x);   // row_half_mirror     == xor 4
  x = dpp_add<0x140>(x);   // row_mirror          == xor 8
  return x;
}

// ---------------------------------------------------------------------------
// Phase A: per-(t,b,h) tile statistics. One wave handles 16 consecutive t of
// one bh (4096 jobs). Per-tile reductions identical to verified R2/R3 code.
// Results staged in LDS [elem][16], flushed with coalesced dwordx4 stores to
// t-major layout: knT2[bh][elem][t], vvT2[bh][elem][t] (=2*v), bbT2[bh][t]
// (=2*beta).
// ---------------------------------------------------------------------------
__global__ __launch_bounds__(256) void stats_kernel(
    const float* __restrict__ x, const float* __restrict__ scale_p,
    const float* __restrict__ bias_p, float* __restrict__ knT2,
    float* __restrict__ vvT2, float* __restrict__ bbT2) {
  const int tid = threadIdx.x;
  const int l   = tid & 63;
  const int m   = l & 7;
  const int g   = l >> 3;
  const int wib = tid >> 6;                 // wave in block 0..3
  const int job = blockIdx.x * 4 + wib;     // 0..4095
  const int bh  = job >> 6;
  const int t0  = (job & 63) << 4;          // chunk of 16 t
  const float sc = scale_p[0], bi = bias_p[0];

  __shared__ float kn_s[4][512];            // [wave][elem*16 + tt]
  __shared__ float vv_s[4][512];
  __shared__ float bb_s[4][16];
  float* ks = kn_s[wib];
  float* vs = vv_s[wib];
  float* bs = bb_s[wib];

  // tile tt lives at x + ((t0+tt)*64 + bh)*1024 ; stride between tt = 65536
  const float4* xp = (const float4*)(x + ((size_t)t0 * 64 + bh) * 1024);
  // preload tile 0
  float4 a0 = xp[l], a1 = xp[l + 64], a2 = xp[l + 128], a3 = xp[l + 192];

  for (int tt = 0; tt < 16; ++tt) {
    float4 b0, b1, b2, b3;
    if (tt < 15) {
      const float4* xn = xp + (size_t)(tt + 1) * 16384;  // +64*1024 floats
      b0 = xn[l]; b1 = xn[l + 64]; b2 = xn[l + 128]; b3 = xn[l + 192];
    }

    // row partials; reduce over m: xor 1,2,4
    float r0 = (a0.x + a0.y) + (a0.z + a0.w);
    float r1 = (a1.x + a1.y) + (a1.z + a1.w);
    float r2 = (a2.x + a2.y) + (a2.z + a2.w);
    float r3 = (a3.x + a3.y) + (a3.z + a3.w);
    r0 += __shfl_xor(r0, 1); r1 += __shfl_xor(r1, 1);
    r2 += __shfl_xor(r2, 1); r3 += __shfl_xor(r3, 1);
    r0 += __shfl_xor(r0, 2); r1 += __shfl_xor(r1, 2);
    r2 += __shfl_xor(r2, 2); r3 += __shfl_xor(r3, 2);
    r0 += __shfl_xor(r0, 4); r1 += __shfl_xor(r1, 4);
    r2 += __shfl_xor(r2, 4); r3 += __shfl_xor(r3, 4);
    // r0..r3 = row sums for rows g, g+8, g+16, g+24 (all lanes)

    // col partials; reduce over g: xor 8,16,32
    float c0 = a0.x + a1.x + a2.x + a3.x;
    float c1 = a0.y + a1.y + a2.y + a3.y;
    float c2 = a0.z + a1.z + a2.z + a3.z;
    float c3 = a0.w + a1.w + a2.w + a3.w;
    c0 += __shfl_xor(c0, 8);  c1 += __shfl_xor(c1, 8);
    c2 += __shfl_xor(c2, 8);  c3 += __shfl_xor(c3, 8);
    c0 += __shfl_xor(c0, 16); c1 += __shfl_xor(c1, 16);
    c2 += __shfl_xor(c2, 16); c3 += __shfl_xor(c3, 16);
    c0 += __shfl_xor(c0, 32); c1 += __shfl_xor(c1, 32);
    c2 += __shfl_xor(c2, 32); c3 += __shfl_xor(c3, 32);
    // c0..c3 = col sums for cols 4m..4m+3 (all lanes)

    // sum(k), ||k||^2 over rows; reduce over g
    float t1 = (r0 + r1) + (r2 + r3);
    float t2 = (r0 * r0 + r1 * r1) + (r2 * r2 + r3 * r3);
    t1 += __shfl_xor(t1, 8);  t2 += __shfl_xor(t2, 8);
    t1 += __shfl_xor(t1, 16); t2 += __shfl_xor(t2, 16);
    t1 += __shfl_xor(t1, 32); t2 += __shfl_xor(t2, 32);
    const float norm = sqrtf(t2) * (1.0f / 32.0f);   // ||k||, k = rowsum/32
    const float kscl = (1.0f / 32.0f) * fast_rcp(norm + 1e-6f);

    if (m == 0) {          // 8 lanes: knorm elements g+8p for this tt
      ks[(g)      * 16 + tt] = r0 * kscl;
      ks[(g + 8)  * 16 + tt] = r1 * kscl;
      ks[(g + 16) * 16 + tt] = r2 * kscl;
      ks[(g + 24) * 16 + tt] = r3 * kscl;
    }
    if (l < 8) {           // lanes 0..7 (m==l): V2 = 2*colmean = colsum/16
      vs[(4 * m)     * 16 + tt] = c0 * (1.0f / 16.0f);
      vs[(4 * m + 1) * 16 + tt] = c1 * (1.0f / 16.0f);
      vs[(4 * m + 2) * 16 + tt] = c2 * (1.0f / 16.0f);
      vs[(4 * m + 3) * 16 + tt] = c3 * (1.0f / 16.0f);
    }
    if (l == 0) {          // B2 = 2*beta
      const float mean = t1 * (1.0f / 1024.0f);
      bs[tt] = 2.0f * fast_sigmoid(sc * mean + bi);
    }

    a0 = b0; a1 = b1; a2 = b2; a3 = b3;
  }

  // flush (same wave wrote the LDS; lgkmcnt ordering only, no barrier needed)
  const size_t rowbase = (size_t)bh * 32 * T_STEPS + t0;
#pragma unroll
  for (int rep = 0; rep < 2; ++rep) {
    const int c = l + rep * 64;       // chunk 0..127
    const int e = c >> 2;             // elem 0..31
    const int q = c & 3;              // quarter of the 16-t run
    const float4 kv = *(const float4*)&ks[e * 16 + q * 4];
    const float4 vv = *(const float4*)&vs[e * 16 + q * 4];
    *(float4*)(knT2 + rowbase + (size_t)e * T_STEPS + q * 4) = kv;
    *(float4*)(vvT2 + rowbase + (size_t)e * T_STEPS + q * 4) = vv;
  }
  if (l < 4) {
    const float4 bv = *(const float4*)&bs[l * 4];
    *(float4*)(bbT2 + (size_t)bh * T_STEPS + t0 + l * 4) = bv;
  }
}

// ---------------------------------------------------------------------------
// Phase B: serial scan. 2048 chains (bh,i); 16 lanes per chain, lane owns
// cols {2s, 2s+1}. Reduction = 4 pure-DPP adds. Stats streamed t-major with
// 16-step double buffering. vv holds V2=2v, bb holds B2=2*beta so the tanh
// argument is B2*S + (V2-2r)*kn with no extra doubling on the serial chain.
// ---------------------------------------------------------------------------
__global__ __launch_bounds__(256, 1) void scan_kernel(
    const float* __restrict__ S0, const float* __restrict__ knT2,
    const float* __restrict__ vvT2, const float* __restrict__ bbT2,
    float* __restrict__ out, float* __restrict__ Sfin) {
  const int tid  = threadIdx.x;
  const int lane = tid & 63;
  const int g    = lane >> 4;                    // group in wave (0..3)
  const int s    = lane & 15;                    // lane in group
  const int w    = blockIdx.x * 4 + (tid >> 6);  // global wave 0..511
  const int bh   = w >> 3;                       // 0..63
  const int i    = (w & 7) * 4 + g;              // 0..31
  const int chain = bh * 32 + i;

  const float2 sini = *(const float2*)(S0 + (size_t)bh * 1024 + i * 32 + 2 * s);
  float Sa = sini.x, Sb = sini.y;

  const float* kn0p = knT2 + ((size_t)bh * 32 + 2 * s) * T_STEPS;
  const float* kn1p = kn0p + T_STEPS;
  const float* vp   = vvT2 + ((size_t)bh * 32 + i) * T_STEPS;
  const float* bp   = bbT2 + (size_t)bh * T_STEPS;

  float Ak0[16], Ak1[16], Av[16], Ab[16];
  float Bk0[16], Bk1[16], Bv[16], Bb[16];

#define LOAD_BLK(K0, K1, VV, BE, TOFF)                                    \
  do {                                                                    \
    const int _to = (TOFF);                                               \
    _Pragma("unroll")                                                     \
    for (int qq = 0; qq < 4; ++qq) {                                      \
      *(float4*)&K0[4 * qq] = *(const float4*)(kn0p + _to + 4 * qq);      \
      *(float4*)&K1[4 * qq] = *(const float4*)(kn1p + _to + 4 * qq);      \
      *(float4*)&VV[4 * qq] = *(const float4*)(vp   + _to + 4 * qq);      \
      *(float4*)&BE[4 * qq] = *(const float4*)(bp   + _to + 4 * qq);      \
    }                                                                     \
  } while (0)

#define STEP_BLK(K0, K1, VV, BE, TBASE)                                   \
  do {                                                                    \
    float oacc = 0.0f;                                                    \
    _Pragma("unroll")                                                     \
    for (int u = 0; u < 16; ++u) {                                        \
      const float c0 = K0[u], c1 = K1[u];                                 \
      const float r  = red16(Sa * c0 + Sb * c1);                          \
      const float D2 = fmaf(-2.0f, r, VV[u]);   /* 2*(v - r) */           \
      const float B2 = BE[u];                                             \
      Sa = fast_tanh2(fmaf(B2, Sa, D2 * c0));                             \
      Sb = fast_tanh2(fmaf(B2, Sb, D2 * c1));                             \
      const float qv = red16(Sa * c0 + Sb * c1);                          \
      const float o  = qv * qv * fast_sigmoid(qv);                        \
      oacc = (u == s) ? o : oacc;                                         \
    }                                                                     \
    outp[(size_t)((TBASE) + s) * 2048] = oacc;                            \
  } while (0)

  float* outp = out + chain;

  LOAD_BLK(Ak0, Ak1, Av, Ab, 0);                 // t = 0..15

  for (int t0 = 0; t0 < T_STEPS; t0 += 32) {
    const int tB = t0 + 16;                      // always < T_STEPS
    const int tA2 = (t0 + 32 < T_STEPS) ? t0 + 32 : t0;  // clamp (dead data)
    LOAD_BLK(Bk0, Bk1, Bv, Bb, tB);              // prefetch block B
    STEP_BLK(Ak0, Ak1, Av, Ab, t0);              // compute block A
    LOAD_BLK(Ak0, Ak1, Av, Ab, tA2);             // prefetch next block A
    STEP_BLK(Bk0, Bk1, Bv, Bb, tB);              // compute block B
  }

#undef LOAD_BLK
#undef STEP_BLK

  float2 sfin; sfin.x = Sa; sfin.y = Sb;
  *(float2*)(Sfin + (size_t)bh * 1024 + i * 32 + 2 * s) = sfin;
}

extern "C" void kernel_launch(void* const* d_in, const int* in_sizes, int n_in,
                              void* d_out, int out_size, void* d_ws, size_t ws_size,
                              hipStream_t stream) {
  const float* x     = (const float*)d_in[0];   // [1024, 8, 8192] f32
  const float* S0    = (const float*)d_in[1];   // [8, 8, 32, 32] f32
  const float* scale = (const float*)d_in[2];   // scalar
  const float* bias  = (const float*)d_in[3];   // scalar
  float* out = (float*)d_out;                   // [1024,8,256] then S_final

  float* knT2 = (float*)d_ws;                   // [64][32][1024]
  float* vvT2 = knT2 + (size_t)NTILE * 32;      // [64][32][1024]  (2*v)
  float* bbT2 = vvT2 + (size_t)NTILE * 32;      // [64][1024]      (2*beta)
  // total ws use: ~16.3 MB

  stats_kernel<<<1024, 256, 0, stream>>>(x, scale, bias, knT2, vvT2, bbT2);

  float* Sfin = out + (size_t)T_STEPS * 2048;   // after 2,097,152 output floats

  // PROBE: scan launched twice (idempotent — identical outputs). The dur_us
  // delta vs the banked 463.8us single-scan run measures one scan dispatch.
  scan_kernel<<<128, 256, 0, stream>>>(S0, knT2, vvT2, bbT2, out, Sfin);
  scan_kernel<<<128, 256, 0, stream>>>(S0, knT2, vvT2, bbT2, out, Sfin);
}

// Round 7
// 529.060 us; speedup vs baseline: 1.0636x; 1.0636x over previous
//
#include <hip/hip_runtime.h>
#include <math.h>

// Problem constants: T=1024, B=8, H=8, N=32. D = H*N*N = 8192.
#define T_STEPS 1024
#define NBH     64          // B*H
#define NTILE   65536       // T*B*H

static __device__ __forceinline__ float fast_rcp(float x) {
  return __builtin_amdgcn_rcpf(x);
}
static __device__ __forceinline__ float fast_sigmoid(float x) {
  return fast_rcp(1.0f + __expf(-x));
}
// tanh(x) where y = 2x is passed: tanh = 1 - 2/(1+e^{2x})
static __device__ __forceinline__ float fast_tanh2(float y) {
  return 1.0f - 2.0f * fast_rcp(1.0f + __expf(y));
}

// DPP add: x + lane-permuted(x). CTRL is a compile-time DPP control.
template <int CTRL>
static __device__ __forceinline__ float dpp_add(float x) {
  int y = __builtin_amdgcn_update_dpp(0, __float_as_int(x), CTRL, 0xF, 0xF, true);
  return x + __int_as_float(y);
}

// Butterfly sum over each 16-lane group; result in all 16 lanes. Pure DPP.
static __device__ __forceinline__ float red16(float x) {
  x = dpp_add<0xB1>(x);    // quad_perm(1,0,3,2)  == xor 1
  x = dpp_add<0x4E>(x);    // quad_perm(2,3,0,1)  == xor 2
  x = dpp_add<0x141>(x);   // row_half_mirror     == xor 4
  x = dpp_add<0x140>(x);   // row_mirror          == xor 8
  return x;
}

// ---------------------------------------------------------------------------
// Phase A: per-(t,b,h) tile statistics. One wave handles 16 consecutive t of
// one bh (4096 jobs). Per-tile reductions identical to verified R2/R3 code.
// 2-deep tile prefetch (3 tiles in flight) to cover ~900cy HBM latency at
// 4 waves/SIMD: compute/tile ~200cy x 4 waves < 900cy, 1-deep was exposed.
// Results staged in LDS [elem][16], flushed with coalesced dwordx4 stores to
// t-major layout: knT2[bh][elem][t], vvT2[bh][elem][t] (=2*v), bbT2[bh][t]
// (=2*beta).
// ---------------------------------------------------------------------------
__global__ __launch_bounds__(256) void stats_kernel(
    const float* __restrict__ x, const float* __restrict__ scale_p,
    const float* __restrict__ bias_p, float* __restrict__ knT2,
    float* __restrict__ vvT2, float* __restrict__ bbT2) {
  const int tid = threadIdx.x;
  const int l   = tid & 63;
  const int m   = l & 7;
  const int g   = l >> 3;
  const int wib = tid >> 6;                 // wave in block 0..3
  const int job = blockIdx.x * 4 + wib;     // 0..4095
  const int bh  = job >> 6;
  const int t0  = (job & 63) << 4;          // chunk of 16 t
  const float sc = scale_p[0], bi = bias_p[0];

  __shared__ float kn_s[4][512];            // [wave][elem*16 + tt]
  __shared__ float vv_s[4][512];
  __shared__ float bb_s[4][16];
  float* ks = kn_s[wib];
  float* vs = vv_s[wib];
  float* bs = bb_s[wib];

  // tile tt lives at x + ((t0+tt)*64 + bh)*1024 ; stride between tt = 65536
  const float4* xp = (const float4*)(x + ((size_t)t0 * 64 + bh) * 1024);
  // preload tiles 0 and 1 (2-deep)
  float4 a0 = xp[l], a1 = xp[l + 64], a2 = xp[l + 128], a3 = xp[l + 192];
  const float4* xq = xp + 16384;
  float4 b0 = xq[l], b1 = xq[l + 64], b2 = xq[l + 128], b3 = xq[l + 192];

  for (int tt = 0; tt < 16; ++tt) {
    float4 n0 = a0, n1 = a1, n2 = a2, n3 = a3;   // dead init (DCE'd)
    if (tt < 14) {
      const float4* xn = xp + (size_t)(tt + 2) * 16384;  // +2*64*1024 floats
      n0 = xn[l]; n1 = xn[l + 64]; n2 = xn[l + 128]; n3 = xn[l + 192];
    }

    // row partials; reduce over m: xor 1,2,4
    float r0 = (a0.x + a0.y) + (a0.z + a0.w);
    float r1 = (a1.x + a1.y) + (a1.z + a1.w);
    float r2 = (a2.x + a2.y) + (a2.z + a2.w);
    float r3 = (a3.x + a3.y) + (a3.z + a3.w);
    r0 += __shfl_xor(r0, 1); r1 += __shfl_xor(r1, 1);
    r2 += __shfl_xor(r2, 1); r3 += __shfl_xor(r3, 1);
    r0 += __shfl_xor(r0, 2); r1 += __shfl_xor(r1, 2);
    r2 += __shfl_xor(r2, 2); r3 += __shfl_xor(r3, 2);
    r0 += __shfl_xor(r0, 4); r1 += __shfl_xor(r1, 4);
    r2 += __shfl_xor(r2, 4); r3 += __shfl_xor(r3, 4);
    // r0..r3 = row sums for rows g, g+8, g+16, g+24 (all lanes)

    // col partials; reduce over g: xor 8,16,32
    float c0 = a0.x + a1.x + a2.x + a3.x;
    float c1 = a0.y + a1.y + a2.y + a3.y;
    float c2 = a0.z + a1.z + a2.z + a3.z;
    float c3 = a0.w + a1.w + a2.w + a3.w;
    c0 += __shfl_xor(c0, 8);  c1 += __shfl_xor(c1, 8);
    c2 += __shfl_xor(c2, 8);  c3 += __shfl_xor(c3, 8);
    c0 += __shfl_xor(c0, 16); c1 += __shfl_xor(c1, 16);
    c2 += __shfl_xor(c2, 16); c3 += __shfl_xor(c3, 16);
    c0 += __shfl_xor(c0, 32); c1 += __shfl_xor(c1, 32);
    c2 += __shfl_xor(c2, 32); c3 += __shfl_xor(c3, 32);
    // c0..c3 = col sums for cols 4m..4m+3 (all lanes)

    // sum(k), ||k||^2 over rows; reduce over g
    float t1 = (r0 + r1) + (r2 + r3);
    float t2 = (r0 * r0 + r1 * r1) + (r2 * r2 + r3 * r3);
    t1 += __shfl_xor(t1, 8);  t2 += __shfl_xor(t2, 8);
    t1 += __shfl_xor(t1, 16); t2 += __shfl_xor(t2, 16);
    t1 += __shfl_xor(t1, 32); t2 += __shfl_xor(t2, 32);
    const float norm = sqrtf(t2) * (1.0f / 32.0f);   // ||k||, k = rowsum/32
    const float kscl = (1.0f / 32.0f) * fast_rcp(norm + 1e-6f);

    if (m == 0) {          // 8 lanes: knorm elements g+8p for this tt
      ks[(g)      * 16 + tt] = r0 * kscl;
      ks[(g + 8)  * 16 + tt] = r1 * kscl;
      ks[(g + 16) * 16 + tt] = r2 * kscl;
      ks[(g + 24) * 16 + tt] = r3 * kscl;
    }
    if (l < 8) {           // lanes 0..7 (m==l): V2 = 2*colmean = colsum/16
      vs[(4 * m)     * 16 + tt] = c0 * (1.0f / 16.0f);
      vs[(4 * m + 1) * 16 + tt] = c1 * (1.0f / 16.0f);
      vs[(4 * m + 2) * 16 + tt] = c2 * (1.0f / 16.0f);
      vs[(4 * m + 3) * 16 + tt] = c3 * (1.0f / 16.0f);
    }
    if (l == 0) {          // B2 = 2*beta
      const float mean = t1 * (1.0f / 1024.0f);
      bs[tt] = 2.0f * fast_sigmoid(sc * mean + bi);
    }

    a0 = b0; a1 = b1; a2 = b2; a3 = b3;
    b0 = n0; b1 = n1; b2 = n2; b3 = n3;
  }

  // flush (same wave wrote the LDS; lgkmcnt ordering only, no barrier needed)
  const size_t rowbase = (size_t)bh * 32 * T_STEPS + t0;
#pragma unroll
  for (int rep = 0; rep < 2; ++rep) {
    const int c = l + rep * 64;       // chunk 0..127
    const int e = c >> 2;             // elem 0..31
    const int q = c & 3;              // quarter of the 16-t run
    const float4 kv = *(const float4*)&ks[e * 16 + q * 4];
    const float4 vv = *(const float4*)&vs[e * 16 + q * 4];
    *(float4*)(knT2 + rowbase + (size_t)e * T_STEPS + q * 4) = kv;
    *(float4*)(vvT2 + rowbase + (size_t)e * T_STEPS + q * 4) = vv;
  }
  if (l < 4) {
    const float4 bv = *(const float4*)&bs[l * 4];
    *(float4*)(bbT2 + (size_t)bh * T_STEPS + t0 + l * 4) = bv;
  }
}

// ---------------------------------------------------------------------------
// Phase B: serial scan, 2-chain ILP version. 2048 chains (bh,i); 16 lanes per
// chain; each 16-lane group now owns TWO chains (i1 = ww*8+g*2, i2 = i1+1)
// whose independent dependence chains interleave in the instruction stream,
// filling the DPP-reduce / exp / rcp stall slots that dominated the 1-chain
// version (measured ~225 cyc/step at 1 wave/SIMD, ~96us total).
// The chain pair shares bh -> shares the k fragments (Ak0/Ak1) and beta (Ab);
// only a second v array + (Sa,Sb) is added. Per-chain math order identical
// to the verified R-series kernel -> bit-identical output.
// 256 waves (64 blocks); chain-pair outputs are adjacent -> float2 stores.
// ---------------------------------------------------------------------------
__global__ __launch_bounds__(256, 1) void scan_kernel(
    const float* __restrict__ S0, const float* __restrict__ knT2,
    const float* __restrict__ vvT2, const float* __restrict__ bbT2,
    float* __restrict__ out, float* __restrict__ Sfin) {
  const int tid  = threadIdx.x;
  const int lane = tid & 63;
  const int g    = lane >> 4;                    // group in wave (0..3)
  const int s    = lane & 15;                    // lane in group
  const int w    = blockIdx.x * 4 + (tid >> 6);  // global wave 0..255
  const int bh   = w >> 2;                       // 0..63
  const int ww   = w & 3;                        // wave within bh
  const int i1   = ww * 8 + g * 2;               // chains i1, i1+1
  const int chain = bh * 32 + i1;

  const float2 si1 = *(const float2*)(S0 + (size_t)bh * 1024 + i1 * 32 + 2 * s);
  const float2 si2 = *(const float2*)(S0 + (size_t)bh * 1024 + (i1 + 1) * 32 + 2 * s);
  float S1a = si1.x, S1b = si1.y;
  float S2a = si2.x, S2b = si2.y;

  const float* kn0p = knT2 + ((size_t)bh * 32 + 2 * s) * T_STEPS;
  const float* kn1p = kn0p + T_STEPS;
  const float* vp1  = vvT2 + ((size_t)bh * 32 + i1) * T_STEPS;
  const float* vp2  = vp1 + T_STEPS;             // i2 = i1+1 is contiguous
  const float* bp   = bbT2 + (size_t)bh * T_STEPS;

  float Ak0[16], Ak1[16], Av1[16], Av2[16], Ab[16];
  float Bk0[16], Bk1[16], Bv1[16], Bv2[16], Bb[16];

#define LOAD_BLK(K0, K1, V1, V2, BE, TOFF)                                \
  do {                                                                    \
    const int _to = (TOFF);                                               \
    _Pragma("unroll")                                                     \
    for (int qq = 0; qq < 4; ++qq) {                                      \
      *(float4*)&K0[4 * qq] = *(const float4*)(kn0p + _to + 4 * qq);      \
      *(float4*)&K1[4 * qq] = *(const float4*)(kn1p + _to + 4 * qq);      \
      *(float4*)&V1[4 * qq] = *(const float4*)(vp1  + _to + 4 * qq);      \
      *(float4*)&V2[4 * qq] = *(const float4*)(vp2  + _to + 4 * qq);      \
      *(float4*)&BE[4 * qq] = *(const float4*)(bp   + _to + 4 * qq);      \
    }                                                                     \
  } while (0)

#define STEP_BLK(K0, K1, V1, V2, BE, TBASE)                               \
  do {                                                                    \
    float oacc1 = 0.0f, oacc2 = 0.0f;                                     \
    _Pragma("unroll")                                                     \
    for (int u = 0; u < 16; ++u) {                                        \
      const float c0 = K0[u], c1 = K1[u];                                 \
      const float B2 = BE[u];                                             \
      const float r1 = red16(S1a * c0 + S1b * c1);                        \
      const float r2 = red16(S2a * c0 + S2b * c1);                        \
      const float D1 = fmaf(-2.0f, r1, V1[u]);   /* 2*(v - r) */          \
      const float D2 = fmaf(-2.0f, r2, V2[u]);                            \
      S1a = fast_tanh2(fmaf(B2, S1a, D1 * c0));                           \
      S1b = fast_tanh2(fmaf(B2, S1b, D1 * c1));                           \
      S2a = fast_tanh2(fmaf(B2, S2a, D2 * c0));                           \
      S2b = fast_tanh2(fmaf(B2, S2b, D2 * c1));                           \
      const float q1 = red16(S1a * c0 + S1b * c1);                        \
      const float q2 = red16(S2a * c0 + S2b * c1);                        \
      const float o1 = q1 * q1 * fast_sigmoid(q1);                        \
      const float o2 = q2 * q2 * fast_sigmoid(q2);                        \
      oacc1 = (u == s) ? o1 : oacc1;                                      \
      oacc2 = (u == s) ? o2 : oacc2;                                      \
    }                                                                     \
    float2 ov; ov.x = oacc1; ov.y = oacc2;                                \
    *(float2*)(outp + (size_t)((TBASE) + s) * 2048) = ov;                 \
  } while (0)

  float* outp = out + chain;                     // chain, chain+1 adjacent

  LOAD_BLK(Ak0, Ak1, Av1, Av2, Ab, 0);           // t = 0..15

  for (int t0 = 0; t0 < T_STEPS; t0 += 32) {
    const int tB = t0 + 16;                      // always < T_STEPS
    const int tA2 = (t0 + 32 < T_STEPS) ? t0 + 32 : t0;  // clamp (dead data)
    LOAD_BLK(Bk0, Bk1, Bv1, Bv2, Bb, tB);        // prefetch block B
    STEP_BLK(Ak0, Ak1, Av1, Av2, Ab, t0);        // compute block A
    LOAD_BLK(Ak0, Ak1, Av1, Av2, Ab, tA2);       // prefetch next block A
    STEP_BLK(Bk0, Bk1, Bv1, Bv2, Bb, tB);        // compute block B
  }

#undef LOAD_BLK
#undef STEP_BLK

  float2 f1; f1.x = S1a; f1.y = S1b;
  float2 f2; f2.x = S2a; f2.y = S2b;
  *(float2*)(Sfin + (size_t)bh * 1024 + i1 * 32 + 2 * s) = f1;
  *(float2*)(Sfin + (size_t)bh * 1024 + (i1 + 1) * 32 + 2 * s) = f2;
}

extern "C" void kernel_launch(void* const* d_in, const int* in_sizes, int n_in,
                              void* d_out, int out_size, void* d_ws, size_t ws_size,
                              hipStream_t stream) {
  const float* x     = (const float*)d_in[0];   // [1024, 8, 8192] f32
  const float* S0    = (const float*)d_in[1];   // [8, 8, 32, 32] f32
  const float* scale = (const float*)d_in[2];   // scalar
  const float* bias  = (const float*)d_in[3];   // scalar
  float* out = (float*)d_out;                   // [1024,8,256] then S_final

  float* knT2 = (float*)d_ws;                   // [64][32][1024]
  float* vvT2 = knT2 + (size_t)NTILE * 32;      // [64][32][1024]  (2*v)
  float* bbT2 = vvT2 + (size_t)NTILE * 32;      // [64][1024]      (2*beta)
  // total ws use: ~16.3 MB

  stats_kernel<<<1024, 256, 0, stream>>>(x, scale, bias, knT2, vvT2, bbT2);

  float* Sfin = out + (size_t)T_STEPS * 2048;   // after 2,097,152 output floats
  scan_kernel<<<64, 256, 0, stream>>>(S0, knT2, vvT2, bbT2, out, Sfin);
}